// Round 1
// baseline (15682.388 us; speedup 1.0000x reference)
//
#include <hip/hip_runtime.h>

typedef __attribute__((ext_vector_type(8))) short short8;
typedef __attribute__((ext_vector_type(4))) float f32x4;

#define TT 512
#define II 512
#define HH 1024

// workspace layout (bytes)
#define OFF_CNT    0u
#define OFF_HPACK  256u        // 2 parity x 2 dir x 32ks x 4mt x 64lane x 8 shorts = 524288 B
#define OFF_C      524544u     // 2 dir x 64 x 1024 fp32 = 524288 B
#define OFF_XPACK  1048832u    // 512 t x 16ks x 4mt x 64lane x 8 shorts = 33554432 B
#define OFF_WPACK  34603264u   // 2 dir x 256cg x 48ks x 64lane x 8 shorts = 25165824 B
#define OFF_BIAS   59769088u   // 2 x 4096 fp32
#define ZERO_BYTES 1048832u

__device__ __forceinline__ unsigned short f2bf(float f) {
  unsigned u = __builtin_bit_cast(unsigned, f);
  u += 0x7FFFu + ((u >> 16) & 1u);   // RNE
  return (unsigned short)(u >> 16);
}
__device__ __forceinline__ float sigm(float x) {
  return __fdividef(1.f, 1.f + __expf(-x));
}
__device__ __forceinline__ float tanh_(float x) {
  return 1.f - __fdividef(2.f, __expf(2.f * x) + 1.f);
}

__global__ void pack_x_kernel(const float* __restrict__ x, short* __restrict__ xpack) {
  int g = blockIdx.x * 256 + threadIdx.x;
  int lane = g & 63;
  int mt = (g >> 6) & 3;
  int ks = (g >> 8) & 15;
  int t = g >> 12;
  int b = mt * 16 + (lane & 15);
  int i = ks * 32 + ((lane >> 4) & 3) * 8;
  const float* src = x + ((size_t)b * TT + t) * II + i;
  float4 v0 = *(const float4*)(src);
  float4 v1 = *(const float4*)(src + 4);
  short8 o;
  o[0] = (short)f2bf(v0.x); o[1] = (short)f2bf(v0.y);
  o[2] = (short)f2bf(v0.z); o[3] = (short)f2bf(v0.w);
  o[4] = (short)f2bf(v1.x); o[5] = (short)f2bf(v1.y);
  o[6] = (short)f2bf(v1.z); o[7] = (short)f2bf(v1.w);
  *(short8*)(xpack + (size_t)g * 8) = o;
}

__global__ void pack_w_kernel(const float* __restrict__ wih_f, const float* __restrict__ whh_f,
                              const float* __restrict__ wih_b, const float* __restrict__ whh_b,
                              short* __restrict__ wpack) {
  int g = blockIdx.x * 256 + threadIdx.x;
  int lane = g & 63;
  int gg = g >> 6;
  int dir = gg / 12288;
  int rem = gg - dir * 12288;
  int cg = rem / 48;
  int ks = rem - cg * 48;
  int col = cg * 16 + (lane & 15);
  int k = ks * 32 + ((lane >> 4) & 3) * 8;
  const float* wih = dir ? wih_b : wih_f;
  const float* whh = dir ? whh_b : whh_f;
  const float* src = (k < II) ? (wih + (size_t)col * II + k)
                              : (whh + (size_t)col * HH + (k - II));
  float4 v0 = *(const float4*)(src);
  float4 v1 = *(const float4*)(src + 4);
  short8 o;
  o[0] = (short)f2bf(v0.x); o[1] = (short)f2bf(v0.y);
  o[2] = (short)f2bf(v0.z); o[3] = (short)f2bf(v0.w);
  o[4] = (short)f2bf(v1.x); o[5] = (short)f2bf(v1.y);
  o[6] = (short)f2bf(v1.z); o[7] = (short)f2bf(v1.w);
  *(short8*)(wpack + (size_t)g * 8) = o;
}

__global__ void pack_bias_kernel(const float* __restrict__ bif, const float* __restrict__ bhf,
                                 const float* __restrict__ bib, const float* __restrict__ bhb,
                                 float* __restrict__ bias) {
  int g = blockIdx.x * 256 + threadIdx.x;
  int dir = g >> 12, n = g & 4095;
  bias[g] = dir ? (bib[n] + bhb[n]) : (bif[n] + bhf[n]);
}

__launch_bounds__(256, 1)
__global__ void lstm_main(const short* __restrict__ xpack, const short* __restrict__ wpack,
                          const float* __restrict__ bias, short* __restrict__ hpack,
                          float* __restrict__ c_ws, unsigned* __restrict__ hcount,
                          float* __restrict__ out) {
  __shared__ float red[4 * 4 * 64 * 16];   // 64 KB

  const int tid = threadIdx.x;
  const int wv = tid >> 6, lane = tid & 63;
  const int blk = blockIdx.x;
  const int dir = blk & 1, jgrp = blk >> 1;
  const int w4 = wv * 4, w8 = wv * 8;

  short8 bfr[4][12];
  {
    const short8* wp = (const short8*)wpack;
    #pragma unroll
    for (int gg = 0; gg < 4; ++gg) {
      size_t base = ((size_t)(dir * 256 + gg * 64 + jgrp) * 48) * 64 + lane;
      #pragma unroll
      for (int i = 0; i < 4; ++i)
        bfr[gg][i] = wp[base + (size_t)(w4 + i) * 64];
      #pragma unroll
      for (int i = 0; i < 8; ++i)
        bfr[gg][4 + i] = wp[base + (size_t)(16 + w8 + i) * 64];
    }
  }

  const short8* xp8 = (const short8*)xpack;
  const short8* hp8 = (const short8*)hpack;
  unsigned* cnt = hcount + dir * 16;

  const int jc = tid & 15, bq = tid >> 4;
  const float b_i = bias[dir * 4096 + 0 * 1024 + jgrp * 16 + jc];
  const float b_f = bias[dir * 4096 + 1 * 1024 + jgrp * 16 + jc];
  const float b_g = bias[dir * 4096 + 2 * 1024 + jgrp * 16 + jc];
  const float b_o = bias[dir * 4096 + 3 * 1024 + jgrp * 16 + jc];

  for (int t = 0; t < TT; ++t) {
    const int par = t & 1;
    const int t_x = dir ? (TT - 1 - t) : t;

    f32x4 acc[4][4];
    #pragma unroll
    for (int gg = 0; gg < 4; ++gg) {
      #pragma unroll
      for (int mt = 0; mt < 4; ++mt) acc[gg][mt] = (f32x4){0.f, 0.f, 0.f, 0.f};
    }

    {  // x-part (independent of other blocks)
      const short8* xbase = xp8 + (size_t)t_x * 4096;
      #pragma unroll
      for (int i = 0; i < 4; ++i) {
        const short8* ab = xbase + (w4 + i) * 256;
        short8 a0 = ab[lane], a1 = ab[64 + lane], a2 = ab[128 + lane], a3 = ab[192 + lane];
        #pragma unroll
        for (int gg = 0; gg < 4; ++gg) {
          acc[gg][0] = __builtin_amdgcn_mfma_f32_16x16x32_bf16(a0, bfr[gg][i], acc[gg][0], 0, 0, 0);
          acc[gg][1] = __builtin_amdgcn_mfma_f32_16x16x32_bf16(a1, bfr[gg][i], acc[gg][1], 0, 0, 0);
          acc[gg][2] = __builtin_amdgcn_mfma_f32_16x16x32_bf16(a2, bfr[gg][i], acc[gg][2], 0, 0, 0);
          acc[gg][3] = __builtin_amdgcn_mfma_f32_16x16x32_bf16(a3, bfr[gg][i], acc[gg][3], 0, 0, 0);
        }
      }
    }

    if (tid == 0) {
      unsigned target = (unsigned)(64 * t);
      while (__hip_atomic_load(cnt, __ATOMIC_ACQUIRE, __HIP_MEMORY_SCOPE_AGENT) < target)
        __builtin_amdgcn_s_sleep(1);
    }
    __syncthreads();
    __threadfence();

    {  // h-part
      const short8* hbase = hp8 + (size_t)(par * 2 + dir) * 8192;
      #pragma unroll
      for (int i = 0; i < 8; ++i) {
        const short8* ab = hbase + (w8 + i) * 256;
        short8 a0 = ab[lane], a1 = ab[64 + lane], a2 = ab[128 + lane], a3 = ab[192 + lane];
        #pragma unroll
        for (int gg = 0; gg < 4; ++gg) {
          acc[gg][0] = __builtin_amdgcn_mfma_f32_16x16x32_bf16(a0, bfr[gg][4 + i], acc[gg][0], 0, 0, 0);
          acc[gg][1] = __builtin_amdgcn_mfma_f32_16x16x32_bf16(a1, bfr[gg][4 + i], acc[gg][1], 0, 0, 0);
          acc[gg][2] = __builtin_amdgcn_mfma_f32_16x16x32_bf16(a2, bfr[gg][4 + i], acc[gg][2], 0, 0, 0);
          acc[gg][3] = __builtin_amdgcn_mfma_f32_16x16x32_bf16(a3, bfr[gg][4 + i], acc[gg][3], 0, 0, 0);
        }
      }
    }

    {  // write partial sums for cross-wave reduction
      int q = lane >> 4, cl = lane & 15;
      #pragma unroll
      for (int gg = 0; gg < 4; ++gg) {
        #pragma unroll
        for (int mt = 0; mt < 4; ++mt) {
          #pragma unroll
          for (int r = 0; r < 4; ++r)
            red[((wv * 4 + gg) * 64 + (mt * 16 + q * 4 + r)) * 16 + cl] = acc[gg][mt][r];
        }
      }
    }
    __syncthreads();

    #pragma unroll
    for (int rr = 0; rr < 4; ++rr) {
      int b = bq + rr * 16;
      float gi = b_i, gf = b_f, gG = b_g, go = b_o;
      #pragma unroll
      for (int w = 0; w < 4; ++w) {
        gi += red[((w * 4 + 0) * 64 + b) * 16 + jc];
        gf += red[((w * 4 + 1) * 64 + b) * 16 + jc];
        gG += red[((w * 4 + 2) * 64 + b) * 16 + jc];
        go += red[((w * 4 + 3) * 64 + b) * 16 + jc];
      }
      int j = jgrp * 16 + jc;
      size_t cidx = (size_t)(dir * 64 + b) * 1024 + j;
      float c_old = c_ws[cidx];
      float cn = sigm(gf) * c_old + sigm(gi) * tanh_(gG);
      c_ws[cidx] = cn;
      float h = sigm(go) * tanh_(cn);
      out[((size_t)(b * TT + t) * 2 + dir) * 1024 + j] = h;
      int lane_ = (b & 15) | (((j >> 3) & 3) << 4);
      size_t hidx = (size_t)((par ^ 1) * 2 + dir) * 65536 +
                    (size_t)(((j >> 5) * 4 + (b >> 4)) * 64 + lane_) * 8 + (j & 7);
      hpack[hidx] = (short)f2bf(h);
      if (t == TT - 1) {
        size_t base2 = (size_t)64 * TT * 2048;
        out[base2 + (size_t)dir * 131072 + (size_t)b * 1024 + j] = h;
        out[base2 + (size_t)dir * 131072 + 65536 + (size_t)b * 1024 + j] = cn;
      }
    }

    __threadfence();
    __syncthreads();
    if (tid == 0)
      __hip_atomic_fetch_add(cnt, 1u, __ATOMIC_RELEASE, __HIP_MEMORY_SCOPE_AGENT);
  }
}

extern "C" void kernel_launch(void* const* d_in, const int* in_sizes, int n_in,
                              void* d_out, int out_size, void* d_ws, size_t ws_size,
                              hipStream_t stream) {
  const float* x     = (const float*)d_in[0];
  const float* wih_f = (const float*)d_in[1];
  const float* whh_f = (const float*)d_in[2];
  const float* bih_f = (const float*)d_in[3];
  const float* bhh_f = (const float*)d_in[4];
  const float* wih_b = (const float*)d_in[5];
  const float* whh_b = (const float*)d_in[6];
  const float* bih_b = (const float*)d_in[7];
  const float* bhh_b = (const float*)d_in[8];

  char* ws = (char*)d_ws;
  unsigned* hcount = (unsigned*)(ws + OFF_CNT);
  short*    hpack  = (short*)(ws + OFF_HPACK);
  float*    c_ws   = (float*)(ws + OFF_C);
  short*    xpack  = (short*)(ws + OFF_XPACK);
  short*    wpack  = (short*)(ws + OFF_WPACK);
  float*    bias   = (float*)(ws + OFF_BIAS);
  float*    out    = (float*)d_out;

  hipMemsetAsync(d_ws, 0, ZERO_BYTES, stream);
  pack_x_kernel<<<8192, 256, 0, stream>>>(x, xpack);
  pack_w_kernel<<<6144, 256, 0, stream>>>(wih_f, whh_f, wih_b, whh_b, wpack);
  pack_bias_kernel<<<32, 256, 0, stream>>>(bih_f, bhh_f, bih_b, bhh_b, bias);
  lstm_main<<<128, 256, 0, stream>>>(xpack, wpack, bias, hpack, c_ws, hcount, out);
}

// Round 2
// 5161.756 us; speedup vs baseline: 3.0382x; 3.0382x over previous
//
#include <hip/hip_runtime.h>

typedef __attribute__((ext_vector_type(8))) short short8;
typedef __attribute__((ext_vector_type(4))) float f32x4;

#define TT 512
#define II 512
#define HH 1024

// workspace layout (bytes)
#define OFF_FLAGS  0u          // 128 flags x 64 B = 8192
#define OFF_HPACK  8192u       // 2 parity x 2 dir x 8192 frag x 16 B = 524288
#define OFF_XPACK  532480u     // 512 t x 4096 frag x 16 B = 33554432
#define OFF_WPACK  34086912u   // 2 dir x 256 cg x 48 ks x 64 lane x 16 B = 25165824
#define OFF_BIAS   59252736u   // 2 x 4096 fp32 = 32768
#define ZERO_BYTES 532480u     // flags + hpack (h0 = 0)

__device__ __forceinline__ unsigned short f2bf(float f) {
  unsigned u = __builtin_bit_cast(unsigned, f);
  u += 0x7FFFu + ((u >> 16) & 1u);   // RNE
  return (unsigned short)(u >> 16);
}
__device__ __forceinline__ float sigm(float x) {
  return __fdividef(1.f, 1.f + __expf(-x));
}
__device__ __forceinline__ float tanh_(float x) {
  return 1.f - __fdividef(2.f, __expf(2.f * x) + 1.f);
}

__global__ void pack_x_kernel(const float* __restrict__ x, short* __restrict__ xpack) {
  int g = blockIdx.x * 256 + threadIdx.x;
  int lane = g & 63;
  int mt = (g >> 6) & 3;
  int ks = (g >> 8) & 15;
  int t = g >> 12;
  int b = mt * 16 + (lane & 15);
  int i = ks * 32 + ((lane >> 4) & 3) * 8;
  const float* src = x + ((size_t)b * TT + t) * II + i;
  float4 v0 = *(const float4*)(src);
  float4 v1 = *(const float4*)(src + 4);
  short8 o;
  o[0] = (short)f2bf(v0.x); o[1] = (short)f2bf(v0.y);
  o[2] = (short)f2bf(v0.z); o[3] = (short)f2bf(v0.w);
  o[4] = (short)f2bf(v1.x); o[5] = (short)f2bf(v1.y);
  o[6] = (short)f2bf(v1.z); o[7] = (short)f2bf(v1.w);
  *(short8*)(xpack + (size_t)g * 8) = o;
}

__global__ void pack_w_kernel(const float* __restrict__ wih_f, const float* __restrict__ whh_f,
                              const float* __restrict__ wih_b, const float* __restrict__ whh_b,
                              short* __restrict__ wpack) {
  int g = blockIdx.x * 256 + threadIdx.x;
  int lane = g & 63;
  int gg = g >> 6;
  int dir = gg / 12288;
  int rem = gg - dir * 12288;
  int cg = rem / 48;
  int ks = rem - cg * 48;
  int col = cg * 16 + (lane & 15);
  int k = ks * 32 + ((lane >> 4) & 3) * 8;
  const float* wih = dir ? wih_b : wih_f;
  const float* whh = dir ? whh_b : whh_f;
  const float* src = (k < II) ? (wih + (size_t)col * II + k)
                              : (whh + (size_t)col * HH + (k - II));
  float4 v0 = *(const float4*)(src);
  float4 v1 = *(const float4*)(src + 4);
  short8 o;
  o[0] = (short)f2bf(v0.x); o[1] = (short)f2bf(v0.y);
  o[2] = (short)f2bf(v0.z); o[3] = (short)f2bf(v0.w);
  o[4] = (short)f2bf(v1.x); o[5] = (short)f2bf(v1.y);
  o[6] = (short)f2bf(v1.z); o[7] = (short)f2bf(v1.w);
  *(short8*)(wpack + (size_t)g * 8) = o;
}

__global__ void pack_bias_kernel(const float* __restrict__ bif, const float* __restrict__ bhf,
                                 const float* __restrict__ bib, const float* __restrict__ bhb,
                                 float* __restrict__ bias) {
  int g = blockIdx.x * 256 + threadIdx.x;
  int dir = g >> 12, n = g & 4095;
  bias[g] = dir ? (bib[n] + bhb[n]) : (bif[n] + bhf[n]);
}

// 128 blocks x 256 threads. block -> (dir = blk&1, jgrp = blk>>1): 16 h-cols.
// 4 waves split K. B panels persist in regs. c state in regs.
// Sync: per-producer flag (64B apart), relaxed sc1 store; consumers poll 64
// flags lane-parallel + one acquire fence (buffer_inv, no wbl2).
__launch_bounds__(256, 1)
__global__ void lstm_main(const short* __restrict__ xpack, const short* __restrict__ wpack,
                          const float* __restrict__ bias, short* __restrict__ hpack,
                          unsigned* __restrict__ flags, float* __restrict__ out) {
  __shared__ float red[4 * 4 * 64 * 16];   // [wv][gate][b64][jc16] = 64 KB

  const int tid = threadIdx.x;
  const int wv = tid >> 6, lane = tid & 63;
  const int blk = blockIdx.x;
  const int dir = blk & 1, jgrp = blk >> 1;
  const int w4 = wv * 4, w8 = wv * 8;

  // ---- preload B fragments (persist across the whole time loop) ----
  short8 bfr[4][12];
  {
    const short8* wp = (const short8*)wpack;
    #pragma unroll
    for (int gg = 0; gg < 4; ++gg) {
      size_t base = ((size_t)(dir * 256 + gg * 64 + jgrp) * 48) * 64 + lane;
      #pragma unroll
      for (int i = 0; i < 4; ++i)
        bfr[gg][i] = wp[base + (size_t)(w4 + i) * 64];
      #pragma unroll
      for (int i = 0; i < 8; ++i)
        bfr[gg][4 + i] = wp[base + (size_t)(16 + w8 + i) * 64];
    }
  }

  const short8* xp8 = (const short8*)xpack;
  const short8* hp8 = (const short8*)hpack;

  // elementwise mapping: thread -> (j0 = jgrp*16 + 2*(tid&7), b in {tid>>3, tid>>3 + 32})
  const int jp = tid & 7, brow = tid >> 3;
  const int j0 = jgrp * 16 + jp * 2;
  float b4[4][2];
  #pragma unroll
  for (int g = 0; g < 4; ++g) {
    b4[g][0] = bias[dir * 4096 + g * 1024 + j0];
    b4[g][1] = bias[dir * 4096 + g * 1024 + j0 + 1];
  }
  float c_reg[2][2] = {{0.f, 0.f}, {0.f, 0.f}};

  const unsigned* myflag_peer = flags + (size_t)(2 * lane + dir) * 16;  // producer blk = 2*lane+dir
  unsigned* myflag = flags + (size_t)blk * 16;

  for (int t = 0; t < TT; ++t) {
    const int par = t & 1;
    const int t_x = dir ? (TT - 1 - t) : t;

    f32x4 acc[4][4];
    #pragma unroll
    for (int gg = 0; gg < 4; ++gg)
      #pragma unroll
      for (int mt = 0; mt < 4; ++mt) acc[gg][mt] = (f32x4){0.f, 0.f, 0.f, 0.f};

    {  // x-part MFMAs (independent of other blocks — overlap the wait)
      const short8* xbase = xp8 + (size_t)t_x * 4096;
      #pragma unroll
      for (int i = 0; i < 4; ++i) {
        const short8* ab = xbase + (w4 + i) * 256;
        short8 a0 = ab[lane], a1 = ab[64 + lane], a2 = ab[128 + lane], a3 = ab[192 + lane];
        #pragma unroll
        for (int gg = 0; gg < 4; ++gg) {
          acc[gg][0] = __builtin_amdgcn_mfma_f32_16x16x32_bf16(a0, bfr[gg][i], acc[gg][0], 0, 0, 0);
          acc[gg][1] = __builtin_amdgcn_mfma_f32_16x16x32_bf16(a1, bfr[gg][i], acc[gg][1], 0, 0, 0);
          acc[gg][2] = __builtin_amdgcn_mfma_f32_16x16x32_bf16(a2, bfr[gg][i], acc[gg][2], 0, 0, 0);
          acc[gg][3] = __builtin_amdgcn_mfma_f32_16x16x32_bf16(a3, bfr[gg][i], acc[gg][3], 0, 0, 0);
        }
      }
    }

    // ---- wait for all 64 producers of this dir to have published step t-1 ----
    if (t) {
      unsigned v = __hip_atomic_load(myflag_peer, __ATOMIC_RELAXED, __HIP_MEMORY_SCOPE_AGENT);
      while (!__all((int)(v >= (unsigned)t))) {
        __builtin_amdgcn_s_sleep(1);
        v = __hip_atomic_load(myflag_peer, __ATOMIC_RELAXED, __HIP_MEMORY_SCOPE_AGENT);
      }
      __builtin_amdgcn_fence(__ATOMIC_ACQUIRE, "agent");  // buffer_inv, no wbl2
    }

    {  // h-part MFMAs
      const short8* hbase = hp8 + (size_t)(par * 2 + dir) * 8192;
      #pragma unroll
      for (int i = 0; i < 8; ++i) {
        const short8* ab = hbase + (w8 + i) * 256;
        short8 a0 = ab[lane], a1 = ab[64 + lane], a2 = ab[128 + lane], a3 = ab[192 + lane];
        #pragma unroll
        for (int gg = 0; gg < 4; ++gg) {
          acc[gg][0] = __builtin_amdgcn_mfma_f32_16x16x32_bf16(a0, bfr[gg][4 + i], acc[gg][0], 0, 0, 0);
          acc[gg][1] = __builtin_amdgcn_mfma_f32_16x16x32_bf16(a1, bfr[gg][4 + i], acc[gg][1], 0, 0, 0);
          acc[gg][2] = __builtin_amdgcn_mfma_f32_16x16x32_bf16(a2, bfr[gg][4 + i], acc[gg][2], 0, 0, 0);
          acc[gg][3] = __builtin_amdgcn_mfma_f32_16x16x32_bf16(a3, bfr[gg][4 + i], acc[gg][3], 0, 0, 0);
        }
      }
    }

    {  // partial sums -> LDS for cross-wave reduction
      int q = lane >> 4, cl = lane & 15;
      #pragma unroll
      for (int gg = 0; gg < 4; ++gg)
        #pragma unroll
        for (int mt = 0; mt < 4; ++mt)
          #pragma unroll
          for (int r = 0; r < 4; ++r)
            red[((wv * 4 + gg) * 64 + (mt * 16 + q * 4 + r)) * 16 + cl] = acc[gg][mt][r];
    }
    __syncthreads();

    // ---- elementwise LSTM update; c in registers ----
    #pragma unroll
    for (int bb = 0; bb < 2; ++bb) {
      int b = brow + 32 * bb;
      float g4[4][2];
      #pragma unroll
      for (int g = 0; g < 4; ++g) { g4[g][0] = b4[g][0]; g4[g][1] = b4[g][1]; }
      #pragma unroll
      for (int w = 0; w < 4; ++w)
        #pragma unroll
        for (int g = 0; g < 4; ++g) {
          const float* rp = &red[((w * 4 + g) * 64 + b) * 16 + jp * 2];
          g4[g][0] += rp[0];
          g4[g][1] += rp[1];
        }
      float h_v[2];
      #pragma unroll
      for (int jj = 0; jj < 2; ++jj) {
        float cn = sigm(g4[1][jj]) * c_reg[bb][jj] + sigm(g4[0][jj]) * tanh_(g4[2][jj]);
        c_reg[bb][jj] = cn;
        h_v[jj] = sigm(g4[3][jj]) * tanh_(cn);
      }
      *(float2*)(out + ((size_t)(b * TT + t) * 2 + dir) * 1024 + j0) = make_float2(h_v[0], h_v[1]);
      // h -> hpack (A-frag layout, next parity) as one packed int via sc1 store
      int lane_ = (b & 15) | (((j0 >> 3) & 3) << 4);
      size_t hidx = (size_t)((par ^ 1) * 2 + dir) * 65536 +
                    (size_t)(((j0 >> 5) * 4 + (b >> 4)) * 64 + lane_) * 8 + (j0 & 7);
      unsigned hv = (unsigned)f2bf(h_v[0]) | ((unsigned)f2bf(h_v[1]) << 16);
      __hip_atomic_store((unsigned*)(hpack + hidx), hv, __ATOMIC_RELAXED, __HIP_MEMORY_SCOPE_AGENT);
      if (t == TT - 1) {
        size_t base2 = (size_t)64 * TT * 2048;
        *(float2*)(out + base2 + (size_t)dir * 131072 + (size_t)b * 1024 + j0) =
            make_float2(h_v[0], h_v[1]);
        *(float2*)(out + base2 + (size_t)dir * 131072 + 65536 + (size_t)b * 1024 + j0) =
            make_float2(c_reg[bb][0], c_reg[bb][1]);
      }
    }

    // ---- publish: syncthreads drains all waves' sc1 stores, then one flag store ----
    __syncthreads();
    if (tid == 0)
      __hip_atomic_store(myflag, (unsigned)(t + 1), __ATOMIC_RELAXED, __HIP_MEMORY_SCOPE_AGENT);
  }
}

extern "C" void kernel_launch(void* const* d_in, const int* in_sizes, int n_in,
                              void* d_out, int out_size, void* d_ws, size_t ws_size,
                              hipStream_t stream) {
  const float* x     = (const float*)d_in[0];
  const float* wih_f = (const float*)d_in[1];
  const float* whh_f = (const float*)d_in[2];
  const float* bih_f = (const float*)d_in[3];
  const float* bhh_f = (const float*)d_in[4];
  const float* wih_b = (const float*)d_in[5];
  const float* whh_b = (const float*)d_in[6];
  const float* bih_b = (const float*)d_in[7];
  const float* bhh_b = (const float*)d_in[8];

  char* ws = (char*)d_ws;
  unsigned* flags  = (unsigned*)(ws + OFF_FLAGS);
  short*    hpack  = (short*)(ws + OFF_HPACK);
  short*    xpack  = (short*)(ws + OFF_XPACK);
  short*    wpack  = (short*)(ws + OFF_WPACK);
  float*    bias   = (float*)(ws + OFF_BIAS);
  float*    out    = (float*)d_out;

  hipMemsetAsync(d_ws, 0, ZERO_BYTES, stream);   // flags + hpack (h0 = 0)
  pack_x_kernel<<<8192, 256, 0, stream>>>(x, xpack);
  pack_w_kernel<<<6144, 256, 0, stream>>>(wih_f, whh_f, wih_b, whh_b, wpack);
  pack_bias_kernel<<<32, 256, 0, stream>>>(bih_f, bhh_f, bih_b, bhh_b, bias);
  lstm_main<<<128, 256, 0, stream>>>(xpack, wpack, bias, hpack, flags, out);
}